// Round 7
// baseline (74.578 us; speedup 1.0000x reference)
//
#include <hip/hip_runtime.h>

#define NN 100000
#define DIN 128
#define DOUT 64
#define NE 1600000

#define BSHIFT 7
#define BROWS 128            // rows per bucket
#define NBB 783              // ceil(100000/128)
#define NBP 1024             // padded key count for place scan
#define CAP 2560             // slots/bucket; mean 2048, sigma ~45 -> +11 sigma
#define QRN 5                // CAP / 512 register-cache depth (exact)
#define EPB 4096             // edges per place-block
#define NBLK 391             // ceil(1600000/4096)
#define GBLK 782             // ceil(100000/128) gemm blocks (512 thr, 128 rows)

// ---------------- ws layout (bytes) ----------------
#define XWB_B  0u                            // ushort[NN*DOUT] = 12.8 MB
#define GCUR_B 12800000u                     // int[NBB] (padded to 8 KB)
#define BPAD_B (GCUR_B + 8192u)              // int2[NBB*CAP] = 16.0 MB
#define WS_NEED (BPAD_B + (unsigned)NBB * CAP * 8u)   // ~28.8 MB

// fused-kernel smem union layout (bytes)
#define SM_DSTL 0u           // int2[EPB]  = 32768
#define SM_SB   32768u       // u16[EPB]   =  8192
#define SM_HIST 40960u       // int[NBP]   =  4096  (later overlaid with base)
#define SM_LOFS 45056u       // int[NBP]   =  4096
#define SM_LCUR 49152u       // int[NBP]   =  4096
#define SM_WTOT 53248u       // int[8]     =    32
#define SM_BYTES 53280u      // 52.0 KB -> 3 blocks/CU (LDS); VGPR caps at 2

typedef unsigned short u16;
typedef unsigned int u32;
typedef __attribute__((ext_vector_type(8))) short v8s;   // 8 bf16 = 4 VGPR
typedef __attribute__((ext_vector_type(4))) float v4f;   // MFMA acc

__device__ __forceinline__ float bf2f(u16 u) {
  return __uint_as_float(((u32)u) << 16);
}
__device__ __forceinline__ u16 f2bf(float f) {
  u32 x = __float_as_uint(f);
  u32 r = x + 0x7fffu + ((x >> 16) & 1u);
  return (u16)(r >> 16);
}

// ---------------------------------------------------------------------------
// fused_gp (round-20): heterogeneous grid. Blocks [0,NBLK) = place (long
// pole, launched first); blocks [NBLK, NBLK+GBLK) = gemm (512 thr, 8 waves
// x 16 rows = 128 rows). place is latency/RMW-bound (~1.3 TB/s effective),
// gemm is streaming-BW-bound -> co-residency overlaps them (serial ~33 us
// -> predicted ~25). smem is a union (52 KB); __launch_bounds__(512,4)
// caps VGPR at 128 so gemm's Bf(64)+xa(32)+acc(16) fits.
// place: base overlays hist in-place after the scan (each slot touched by
// exactly one thread in the claim phase) -- saves 4 KB vs place5.
// ---------------------------------------------------------------------------
__global__ __launch_bounds__(512, 4) void fused_gp_kernel(
    const float* __restrict__ x, const float* __restrict__ w,
    u16* __restrict__ xwb,
    const int* __restrict__ erow, const int* __restrict__ ecol,
    const float* __restrict__ eval_, int* __restrict__ gcur,
    int2* __restrict__ bpad) {
  __shared__ __align__(16) char smem[SM_BYTES];
  const int t = threadIdx.x;
  const int lane = t & 63;
  const int wv = t >> 6;                  // 0..7

  if (blockIdx.x < NBLK) {
    // ------------------------- place branch --------------------------------
    int2* dstl = (int2*)(smem + SM_DSTL);
    u16*  sb   = (u16*)(smem + SM_SB);
    int*  hist = (int*)(smem + SM_HIST);  // later holds base[]
    int*  lofs = (int*)(smem + SM_LOFS);
    int*  lcur = (int*)(smem + SM_LCUR);
    int*  wtot = (int*)(smem + SM_WTOT);

    const int e0 = blockIdx.x * EPB;
    const int e1 = min(e0 + EPB, NE);
    const int ecount = e1 - e0;

    hist[t] = 0;        hist[t + 512] = 0;
    lcur[t] = 0;        lcur[t + 512] = 0;
    __syncthreads();

    // A: histogram; cache all edge data in registers (independent loads)
    int er[8], ec[8];
    float ev[8];
    #pragma unroll
    for (int k = 0; k < 8; ++k) {
      const int e = e0 + t + k * 512;
      if (e < e1) {
        er[k] = erow[e];
        ec[k] = ecol[e];
        ev[k] = eval_[e];
        atomicAdd(&hist[er[k] >> BSHIFT], 1);
      } else {
        er[k] = -1;
      }
    }
    __syncthreads();

    // B: exclusive scan over 1024 keys (pair-per-thread + wave shfl)
    const int ha = hist[2 * t], hb = hist[2 * t + 1];
    const int ps = ha + hb;
    int s = ps;
    #pragma unroll
    for (int o = 1; o < 64; o <<= 1) {
      const int u = __shfl_up(s, o);
      if (lane >= o) s += u;
    }
    if (lane == 63) wtot[wv] = s;
    __syncthreads();
    int woff = 0;
    #pragma unroll
    for (int w8 = 0; w8 < 8; ++w8) woff += (w8 < wv) ? wtot[w8] : 0;
    const int excl = woff + s - ps;
    lofs[2 * t]     = excl;
    lofs[2 * t + 1] = excl + ha;
    // claim bucket ranges; write base INTO hist (each slot is read+written
    // by exactly this thread in this phase -> no race)
    #pragma unroll
    for (int i = t; i < NBP; i += 512) {
      const int h = hist[i];
      hist[i] = (h && i < NBB) ? atomicAdd(&gcur[i], h) : 0;
    }
    __syncthreads();

    // C: rank + scatter payload into LDS sorted order (pure LDS)
    #pragma unroll
    for (int k = 0; k < 8; ++k) {
      if (er[k] >= 0) {
        const int b = er[k] >> BSHIFT;
        const int pos = lofs[b] + atomicAdd(&lcur[b], 1);
        dstl[pos] = make_int2(((er[k] & (BROWS - 1)) << 17) | ec[k],
                              __float_as_int(ev[k]));
        sb[pos] = (u16)b;
      }
    }
    __syncthreads();

    // D: stream sorted payload to bpad (runs of ~5.2 edges = contiguous)
    for (int p = t; p < ecount; p += 512) {
      const int b = sb[p];
      const int rk = hist[b] + (p - lofs[b]);   // hist[] holds base now
      if (rk < CAP) bpad[(long)b * CAP + rk] = dstl[p];
    }
    return;
  }

  // --------------------------- gemm branch ---------------------------------
  u16* wlds = (u16*)smem;                 // 16 KB, fragment-order
  const int gb = blockIdx.x - NBLK;

  #pragma unroll
  for (int pi = 0; pi < 2; ++pi) {
    const int p = t * 2 + pi;             // 1024 fragments / 512 threads
    const int f = p >> 6, lp = p & 63;
    const int kc = f >> 2, nc = f & 3;
    const int kg = lp >> 4, lr = lp & 15;
    const int kbase = kc * 32 + kg * 8;
    u32 pk[4];
    #pragma unroll
    for (int h = 0; h < 4; ++h) {
      const u32 lo = f2bf(w[(kbase + 2 * h)     * DOUT + nc * 16 + lr]);
      const u32 hi = f2bf(w[(kbase + 2 * h + 1) * DOUT + nc * 16 + lr]);
      pk[h] = lo | (hi << 16);
    }
    *reinterpret_cast<uint4*>(&wlds[p * 8]) =
        make_uint4(pk[0], pk[1], pk[2], pk[3]);
  }
  __syncthreads();

  const int row0 = gb * 128 + wv * 16;
  if (row0 >= NN) return;                 // safe: after the only barrier
  const int lrow = lane & 15;
  const int lkg  = lane >> 4;

  v8s Bf[4][4];
  #pragma unroll
  for (int kc = 0; kc < 4; ++kc)
    #pragma unroll
    for (int nc = 0; nc < 4; ++nc)
      Bf[kc][nc] = *reinterpret_cast<const v8s*>(
          &wlds[((kc * 4 + nc) * 64 + lane) * 8]);

  const float* xr = x + (size_t)(row0 + lrow) * DIN + lkg * 8;
  float4 xa[4][2];
  #pragma unroll
  for (int kc = 0; kc < 4; ++kc) {
    xa[kc][0] = *reinterpret_cast<const float4*>(xr + kc * 32);
    xa[kc][1] = *reinterpret_cast<const float4*>(xr + kc * 32 + 4);
  }

  v4f acc[4];
  #pragma unroll
  for (int nc = 0; nc < 4; ++nc) acc[nc] = (v4f){0.f, 0.f, 0.f, 0.f};

  #pragma unroll
  for (int kc = 0; kc < 4; ++kc) {
    v8s Af;
    Af[0] = (short)f2bf(xa[kc][0].x);
    Af[1] = (short)f2bf(xa[kc][0].y);
    Af[2] = (short)f2bf(xa[kc][0].z);
    Af[3] = (short)f2bf(xa[kc][0].w);
    Af[4] = (short)f2bf(xa[kc][1].x);
    Af[5] = (short)f2bf(xa[kc][1].y);
    Af[6] = (short)f2bf(xa[kc][1].z);
    Af[7] = (short)f2bf(xa[kc][1].w);
    #pragma unroll
    for (int nc = 0; nc < 4; ++nc)
      acc[nc] = __builtin_amdgcn_mfma_f32_16x16x32_bf16(Af, Bf[kc][nc],
                                                        acc[nc], 0, 0, 0);
  }

  #pragma unroll
  for (int nc = 0; nc < 4; ++nc)
    #pragma unroll
    for (int j = 0; j < 4; ++j)
      xwb[(size_t)(row0 + lkg * 4 + j) * DOUT + nc * 16 + lrow] =
          f2bf(acc[nc][j]);
}

// ---------------------------------------------------------------------------
// agg7 (round-19, kept verbatim): one 512-thr block per 128-row bucket,
// grid 783; segment reg-cached in exactly qr[5] (zero read amplification),
// hist/scan/sort into LDS, then the validated slot-vectorized loop.
// ---------------------------------------------------------------------------
__global__ __launch_bounds__(512) void agg7_kernel(
    const int* __restrict__ gcur, const int2* __restrict__ bpad,
    const u16* __restrict__ xwb, float* __restrict__ out) {
  __shared__ int2 dst[CAP];        // 20480 B
  __shared__ int  hist[BROWS];
  __shared__ int  lptr[BROWS + 1];
  __shared__ int  cur[BROWS];

  const int bucket = blockIdx.x;
  const int t = threadIdx.x;
  const int count = min(gcur[bucket], CAP);
  const long sbase = (long)bucket * CAP;

  if (t < BROWS) hist[t] = 0;
  __syncthreads();

  // single streaming read of this bucket's segment into registers
  int2 qr[QRN];
  #pragma unroll
  for (int k = 0; k < QRN; ++k) {
    const int e = t + k * 512;
    qr[k].x = -1;
    if (e < count) {
      qr[k] = bpad[sbase + e];
      atomicAdd(&hist[(qr[k].x >> 17) & (BROWS - 1)], 1);
    }
  }
  __syncthreads();

  // exclusive scan over 128 rows: pair-per-thread on one wave
  if (t < 64) {
    const int h0 = hist[2 * t], h1 = hist[2 * t + 1];
    const int ps = h0 + h1;
    int s = ps;
    #pragma unroll
    for (int o = 1; o < 64; o <<= 1) {
      const int u = __shfl_up(s, o);
      if (t >= o) s += u;
    }
    const int excl = s - ps;
    lptr[2 * t]     = excl;        cur[2 * t]     = excl;
    lptr[2 * t + 1] = excl + h0;   cur[2 * t + 1] = excl + h0;
    if (t == 63) lptr[BROWS] = s;
  }
  __syncthreads();

  #pragma unroll
  for (int k = 0; k < QRN; ++k) {
    if (qr[k].x >= 0) {
      const int r = (qr[k].x >> 17) & (BROWS - 1);
      const int pos = atomicAdd(&cur[r], 1);
      dst[pos] = qr[k];
    }
  }
  __syncthreads();

  const int lane = t & 63;
  const int wave = t >> 6;         // 0..7
  const int slot = lane >> 4;      // 0..3  (edge sub-slot)
  const int li   = lane & 15;      // 0..15 (covers 4 cols each via dwordx2)
  const int row0 = bucket << BSHIFT;
  const int cmax = count - 1;

  for (int r = wave; r < BROWS; r += 8) {
    const int row = row0 + r;
    if (row >= NN) break;
    const int s = lptr[r], en = lptr[r + 1];
    float a0 = 0.f, a1 = 0.f, a2 = 0.f, a3 = 0.f;
    for (int e = s; e < en; e += 8) {
      {
        const int idx = e + slot;
        const int2 q = dst[min(idx, cmax)];
        const float v = (idx < en) ? __int_as_float(q.y) : 0.f;
        const u32 col = (u32)q.x & 0x1FFFFu;
        const uint2 g = *reinterpret_cast<const uint2*>(
            xwb + (size_t)col * DOUT + li * 4);
        a0 = fmaf(v, __uint_as_float(g.x << 16), a0);
        a1 = fmaf(v, __uint_as_float(g.x & 0xFFFF0000u), a1);
        a2 = fmaf(v, __uint_as_float(g.y << 16), a2);
        a3 = fmaf(v, __uint_as_float(g.y & 0xFFFF0000u), a3);
      }
      {
        const int idx = e + 4 + slot;
        const int2 q = dst[min(idx, cmax)];
        const float v = (idx < en) ? __int_as_float(q.y) : 0.f;
        const u32 col = (u32)q.x & 0x1FFFFu;
        const uint2 g = *reinterpret_cast<const uint2*>(
            xwb + (size_t)col * DOUT + li * 4);
        a0 = fmaf(v, __uint_as_float(g.x << 16), a0);
        a1 = fmaf(v, __uint_as_float(g.x & 0xFFFF0000u), a1);
        a2 = fmaf(v, __uint_as_float(g.y << 16), a2);
        a3 = fmaf(v, __uint_as_float(g.y & 0xFFFF0000u), a3);
      }
    }
    // cross-slot reduce: all 4 slot copies of li end up holding the sum
    a0 += __shfl_xor(a0, 16); a0 += __shfl_xor(a0, 32);
    a1 += __shfl_xor(a1, 16); a1 += __shfl_xor(a1, 32);
    a2 += __shfl_xor(a2, 16); a2 += __shfl_xor(a2, 32);
    a3 += __shfl_xor(a3, 16); a3 += __shfl_xor(a3, 32);
    if (slot == 0) {
      float4 o;
      o.x = fmaxf(a0, 0.f); o.y = fmaxf(a1, 0.f);
      o.z = fmaxf(a2, 0.f); o.w = fmaxf(a3, 0.f);
      *reinterpret_cast<float4*>(&out[(size_t)row * DOUT + li * 4]) = o;
    }
  }
}

// ----------------------- fallback (atomic) path ----------------------------
__global__ __launch_bounds__(256) void gemm_kernel(
    const float* __restrict__ x, const float* __restrict__ w,
    u16* __restrict__ xwb) {
  __shared__ u16 wlds[16 * 64 * 8];   // 16 KB
  const int t = threadIdx.x;
  const int lane = t & 63;
  const int wv = t >> 6;

  #pragma unroll
  for (int pi = 0; pi < 4; ++pi) {
    const int p = t * 4 + pi;
    const int f = p >> 6, lp = p & 63;
    const int kc = f >> 2, nc = f & 3;
    const int kg = lp >> 4, lr = lp & 15;
    const int kbase = kc * 32 + kg * 8;
    u32 pk[4];
    #pragma unroll
    for (int h = 0; h < 4; ++h) {
      const u32 lo = f2bf(w[(kbase + 2 * h)     * DOUT + nc * 16 + lr]);
      const u32 hi = f2bf(w[(kbase + 2 * h + 1) * DOUT + nc * 16 + lr]);
      pk[h] = lo | (hi << 16);
    }
    *reinterpret_cast<uint4*>(&wlds[p * 8]) =
        make_uint4(pk[0], pk[1], pk[2], pk[3]);
  }
  __syncthreads();

  const int row0 = blockIdx.x * 64 + wv * 16;
  if (row0 >= NN) return;
  const int lrow = lane & 15;
  const int lkg  = lane >> 4;

  v8s Bf[4][4];
  #pragma unroll
  for (int kc = 0; kc < 4; ++kc)
    #pragma unroll
    for (int nc = 0; nc < 4; ++nc)
      Bf[kc][nc] = *reinterpret_cast<const v8s*>(
          &wlds[((kc * 4 + nc) * 64 + lane) * 8]);

  const float* xr = x + (size_t)(row0 + lrow) * DIN + lkg * 8;
  float4 xa[4][2];
  #pragma unroll
  for (int kc = 0; kc < 4; ++kc) {
    xa[kc][0] = *reinterpret_cast<const float4*>(xr + kc * 32);
    xa[kc][1] = *reinterpret_cast<const float4*>(xr + kc * 32 + 4);
  }

  v4f acc[4];
  #pragma unroll
  for (int nc = 0; nc < 4; ++nc) acc[nc] = (v4f){0.f, 0.f, 0.f, 0.f};

  #pragma unroll
  for (int kc = 0; kc < 4; ++kc) {
    v8s Af;
    Af[0] = (short)f2bf(xa[kc][0].x);
    Af[1] = (short)f2bf(xa[kc][0].y);
    Af[2] = (short)f2bf(xa[kc][0].z);
    Af[3] = (short)f2bf(xa[kc][0].w);
    Af[4] = (short)f2bf(xa[kc][1].x);
    Af[5] = (short)f2bf(xa[kc][1].y);
    Af[6] = (short)f2bf(xa[kc][1].z);
    Af[7] = (short)f2bf(xa[kc][1].w);
    #pragma unroll
    for (int nc = 0; nc < 4; ++nc)
      acc[nc] = __builtin_amdgcn_mfma_f32_16x16x32_bf16(Af, Bf[kc][nc],
                                                        acc[nc], 0, 0, 0);
  }

  #pragma unroll
  for (int nc = 0; nc < 4; ++nc)
    #pragma unroll
    for (int j = 0; j < 4; ++j)
      xwb[(size_t)(row0 + lkg * 4 + j) * DOUT + nc * 16 + lrow] =
          f2bf(acc[nc][j]);
}

__global__ __launch_bounds__(256) void scatter_kernel(
    const int* __restrict__ erow, const int* __restrict__ ecol,
    const float* __restrict__ eval_, const u16* __restrict__ xwb,
    float* __restrict__ out) {
  const int wave = (blockIdx.x * blockDim.x + threadIdx.x) >> 6;
  const int lane = threadIdx.x & 63;
  const int nwaves = (gridDim.x * blockDim.x) >> 6;
  const int per = (NE + nwaves - 1) / nwaves;
  const int e0 = wave * per;
  const int e1 = min(e0 + per, NE);
  for (int base = e0; base < e1; base += 64) {
    const int e = base + lane;
    int r = 0, c = 0; float v = 0.f;
    if (e < e1) { r = erow[e]; c = ecol[e]; v = eval_[e]; }
    const int cnt = min(64, e1 - base);
    for (int j = 0; j < cnt; ++j) {
      const int rj = __shfl(r, j);
      const int cj = __shfl(c, j);
      const float vj = __shfl(v, j);
      atomicAdd(&out[rj * DOUT + lane], vj * bf2f(xwb[cj * DOUT + lane]));
    }
  }
}

__global__ __launch_bounds__(256) void finish_kernel(float* __restrict__ out) {
  const int idx = (blockIdx.x * blockDim.x + threadIdx.x) * 4;
  if (idx < NN * DOUT) {
    float4 a = *reinterpret_cast<const float4*>(&out[idx]);
    a.x = fmaxf(a.x, 0.f); a.y = fmaxf(a.y, 0.f);
    a.z = fmaxf(a.z, 0.f); a.w = fmaxf(a.w, 0.f);
    *reinterpret_cast<float4*>(&out[idx]) = a;
  }
}

extern "C" void kernel_launch(void* const* d_in, const int* in_sizes, int n_in,
                              void* d_out, int out_size, void* d_ws, size_t ws_size,
                              hipStream_t stream) {
  const float* x     = (const float*)d_in[0];
  const int*   erow  = (const int*)d_in[1];
  const int*   ecol  = (const int*)d_in[2];
  const float* eval_ = (const float*)d_in[3];
  const float* w     = (const float*)d_in[4];
  float* out = (float*)d_out;

  char* ws = (char*)d_ws;
  u16* xwb = (u16*)(ws + XWB_B);

  if (ws_size >= (size_t)WS_NEED) {
    int*  gcur = (int*)(ws + GCUR_B);
    int2* bpad = (int2*)(ws + BPAD_B);

    hipMemsetAsync(gcur, 0, NBB * 4, stream);
    fused_gp_kernel<<<NBLK + GBLK, 512, 0, stream>>>(
        x, w, xwb, erow, ecol, eval_, gcur, bpad);
    agg7_kernel<<<NBB, 512, 0, stream>>>(gcur, bpad, xwb, out);
  } else {
    gemm_kernel<<<(NN + 63) / 64, 256, 0, stream>>>(x, w, xwb);
    hipMemsetAsync(d_out, 0, (size_t)NN * DOUT * sizeof(float), stream);
    scatter_kernel<<<2048, 256, 0, stream>>>(erow, ecol, eval_, xwb, out);
    const int fin_grid = (NN * DOUT / 4 + 255) / 256;
    finish_kernel<<<fin_grid, 256, 0, stream>>>(out);
  }
}